// Round 4
// baseline (239.634 us; speedup 1.0000x reference)
//
#include <hip/hip_runtime.h>
#include <hip/hip_bf16.h>
#include <math.h>

#define B_  16
#define C_  64
#define HW_ 128
#define E_  8
#define GH_ 16

typedef __attribute__((ext_vector_type(8))) short short8;
typedef __attribute__((ext_vector_type(4))) float float4v;

// conv tiling: 32 wide x 8 high spatial tile, 4 waves, wave = 4 Mtiles x 4 Ntiles
#define TW 32
#define TH 8
#define HALO_W 34
#define HALO_H 10
#define NPIX (HALO_H * HALO_W)          // 340
// per-half xs: [340 px][4 slots][8 ci] shorts = 21760 B; slot = g ^ ((c>>2)&3)
#define XS_SHORTS (NPIX * 32)
// epilogue lout: 32 co x 292 floats = 37376 B (aliases xs)
#define SMEM_BYTES 37376
// per-sample packed weights: [9 pos][2 khalf][4 quad][64 co][8 ci] bf16
#define WB_PER_B (9 * 2 * 4 * 64 * 8)   // 36864

// ---------------------------------------------------------------------------
// K1: global average pool. One block per (b,c); float4 loads, no atomics.
// ---------------------------------------------------------------------------
__global__ __launch_bounds__(256) void pool_kernel(const float* __restrict__ x,
                                                   float* __restrict__ pooled) {
  const int bc = blockIdx.x;
  const float4v* p4 = (const float4v*)(x + (size_t)bc * (HW_ * HW_));
  float4v s4 = {0.f, 0.f, 0.f, 0.f};
  for (int i = threadIdx.x; i < (HW_ * HW_) / 4; i += 256) s4 += p4[i];
  float s = (s4.x + s4.y) + (s4.z + s4.w);
#pragma unroll
  for (int off = 32; off > 0; off >>= 1) s += __shfl_down(s, off, 64);
  __shared__ float red[4];
  if ((threadIdx.x & 63) == 0) red[threadIdx.x >> 6] = s;
  __syncthreads();
  if (threadIdx.x == 0)
    pooled[bc] = (red[0] + red[1] + red[2] + red[3]) * (1.0f / (HW_ * HW_));
}

// ---------------------------------------------------------------------------
// K2: fused gate (recomputed per block, trivial) + weight combine into packed
// bf16 B-fragment layout, with the residual identity folded into the center
// tap (co==ci, pos==4). Also writes combined bias for this block's 8 co.
// block = (b, co-group of 8); grid = 128.
// ---------------------------------------------------------------------------
__global__ __launch_bounds__(256) void combine_kernel(
    const float* __restrict__ w_exp, const float* __restrict__ pooled,
    const float* __restrict__ wg1, const float* __restrict__ bg1,
    const float* __restrict__ wg2, const float* __restrict__ bg2,
    const float* __restrict__ b_exp, __hip_bfloat16* __restrict__ wB,
    float* __restrict__ bcomb) {
  __shared__ float wtmp[8 * 576];   // 18.4 KB
  __shared__ float hsh[GH_];
  __shared__ float psh[E_];
  const int t = threadIdx.x;
  const int b = blockIdx.x >> 3;
  const int cog = blockIdx.x & 7;

  // ---- gate for sample b (redundant per cog-block; tiny) ----
  if (t < GH_) {
    float s = bg1[t];
    for (int c = 0; c < C_; c++)
      s = fmaf(pooled[b * C_ + c], wg1[c * GH_ + t], s);
    hsh[t] = fmaxf(s, 0.f);
  }
  __syncthreads();
  if (t == 0) {
    float p[E_];
    float mx = -1e30f;
#pragma unroll
    for (int e = 0; e < E_; e++) {
      float s = bg2[e];
#pragma unroll
      for (int g = 0; g < GH_; g++) s = fmaf(hsh[g], wg2[g * E_ + e], s);
      p[e] = s;
      mx = fmaxf(mx, s);
    }
    float sum = 0.f;
#pragma unroll
    for (int e = 0; e < E_; e++) { p[e] = expf(p[e] - mx); sum += p[e]; }
    const float inv = 1.0f / sum;
#pragma unroll
    for (int e = 0; e < E_; e++) p[e] *= inv;
    int i1 = 0;
#pragma unroll
    for (int e = 1; e < E_; e++) if (p[e] > p[i1]) i1 = e;
    int i2 = -1;
#pragma unroll
    for (int e = 0; e < E_; e++) {
      if (e == i1) continue;
      if (i2 < 0 || p[e] > p[i2]) i2 = e;
    }
    const float denom = p[i1] + p[i2] + 1e-8f;
#pragma unroll
    for (int e = 0; e < E_; e++)
      psh[e] = (e == i1 || e == i2) ? (p[e] / denom) : 0.f;
  }
  __syncthreads();
  float pb[E_];
#pragma unroll
  for (int e = 0; e < E_; e++) pb[e] = psh[e];

  // ---- coalesced combine: 8 co x 576 contiguous floats per expert ----
  const size_t src0 = (size_t)cog * 8 * 576;
  for (int i = t; i < 4608; i += 256) {
    float s = 0.f;
#pragma unroll
    for (int e = 0; e < E_; e++)
      s = fmaf(pb[e], w_exp[(size_t)e * (C_ * 576) + src0 + i], s);
    wtmp[i] = s;
  }
  __syncthreads();
  // ---- packed write (+ identity at center tap) ----
  for (int i = t; i < 4608; i += 256) {
    const int j = i & 7;
    const int co_l = (i >> 3) & 7;
    const int rest = i >> 6;          // 0..71
    const int quad = rest & 3;
    const int khalf = (rest >> 2) & 1;
    const int pos = rest >> 3;
    const int ci = khalf * 32 + quad * 8 + j;
    const int co = cog * 8 + co_l;
    float v = wtmp[co_l * 576 + ci * 9 + pos];
    if (pos == 4 && co == ci) v += 1.0f;   // fold residual into conv
    wB[(size_t)b * WB_PER_B +
       ((((pos * 2 + khalf) * 4 + quad) * 64) + co) * 8 + j] =
        __float2bfloat16(v);
  }
  if (t < 8) {
    const int co = cog * 8 + t;
    float s = 0.f;
#pragma unroll
    for (int e = 0; e < E_; e++) s = fmaf(pb[e], b_exp[e * C_ + co], s);
    bcomb[b * C_ + co] = s;
  }
}

// ---------------------------------------------------------------------------
// K4: implicit-GEMM conv (mfma_f32_16x16x32_bf16). Stages fp32 NCHW x
// directly into bf16 LDS (in-flight convert, paired-ci b32 pack). Residual
// is folded into wB; epilogue adds bias only. grid (64 tiles, 16 samples).
// ---------------------------------------------------------------------------
__global__ __launch_bounds__(256, 4) void conv_kernel(
    const float* __restrict__ x, const __hip_bfloat16* __restrict__ wB,
    const float* __restrict__ bcomb, float* __restrict__ out) {
  __shared__ __align__(16) char smem[SMEM_BYTES];
  short* xs = (short*)smem;
  float* lout = (float*)smem;

  const int t = threadIdx.x;
  const int tile = blockIdx.x;
  const int b = blockIdx.y;
  const int tx = (tile & 3) * TW;
  const int ty = (tile >> 2) * TH;
  const int wave = t >> 6;
  const int L = t & 63;
  const int n16 = L & 15;
  const int quad = L >> 4;

  // staging decode (per-thread constants; i = t + it*256 keeps low 8 bits)
  const int w0 = t >> 6;                 // 0..3
  const int c4 = t & 15;                 // 0..15 (valid 0..9)
  const int psub = (t >> 4) & 3;         // ci-pair within 8-group
  const bool c4ok = (c4 <= 9);
  const int gw0 = tx + 4 * (c4 - 1);
  const bool gwok = (gw0 >= 0) && (gw0 <= HW_ - 4);

  float4v acc[4][4];
#pragma unroll
  for (int mt = 0; mt < 4; mt++)
#pragma unroll
    for (int nt = 0; nt < 4; nt++) acc[mt][nt] = (float4v)0.f;

  for (int half = 0; half < 2; half++) {
    __syncthreads();
    // ---- stage one 32-ci half of the 10x34 fp32 halo -> bf16 LDS ----
#pragma unroll
    for (int it = 0; it < 10; it++) {
      const int q = w0 + it * 4;         // 0..39, bijective over (w0,it)
      const int ph = q / 10;             // ci 8-group 0..3
      const int r = q - ph * 10;         // halo row 0..9
      const int gh = ty + r - 1;
      const int ci = half * 32 + ph * 8 + psub * 2;
      float4v vA = {0.f, 0.f, 0.f, 0.f};
      float4v vB = {0.f, 0.f, 0.f, 0.f};
      const bool lv = c4ok && gwok && ((unsigned)gh < (unsigned)HW_);
      if (lv) {
        const float* pA = x + ((size_t)(b * C_ + ci) * HW_ + gh) * HW_ + gw0;
        vA = *(const float4v*)pA;
        vB = *(const float4v*)(pA + HW_ * HW_);
      }
#pragma unroll
      for (int kk = 0; kk < 4; kk++) {
        const int cl = 4 * c4 + kk - 3;  // halo col 0..33
        if (c4ok && ((unsigned)cl < 34u)) {
          const int p = r * HALO_W + cl;
          const int slot = ph ^ ((cl >> 2) & 3);
          __hip_bfloat16 ba = __float2bfloat16(vA[kk]);
          __hip_bfloat16 bb = __float2bfloat16(vB[kk]);
          const unsigned pack = (unsigned)*(unsigned short*)&ba |
                                ((unsigned)*(unsigned short*)&bb << 16);
          *(unsigned*)&xs[p * 32 + slot * 8 + psub * 2] = pack;
        }
      }
    }
    __syncthreads();

    // ---- B fragments: double-buffered prefetch from global (L2-hot) ----
    const __hip_bfloat16* wBh =
        wB + (size_t)b * WB_PER_B + (size_t)(half * 4 + quad) * 512 + n16 * 8;
    short8 bf[2][4];
#pragma unroll
    for (int nt = 0; nt < 4; nt++)
      bf[0][nt] = *(const short8*)(wBh + nt * 128);

#pragma unroll
    for (int pos = 0; pos < 9; pos++) {
      const int cur = pos & 1;
      if (pos < 8) {
#pragma unroll
        for (int nt = 0; nt < 4; nt++)
          bf[cur ^ 1][nt] =
              *(const short8*)(wBh + (size_t)(pos + 1) * 4096 + nt * 128);
      }
      const int kh = pos / 3;
      const int kw = pos - kh * 3;
      short8 a[4];
#pragma unroll
      for (int mt = 0; mt < 4; mt++) {
        const int mtg = wave * 4 + mt;
        const int pr = mtg >> 1;
        const int cb = (mtg & 1) * 16;
        const int hr = pr + kh;
        const int hc = cb + n16 + kw;
        const int p = hr * HALO_W + hc;
        const int slot = quad ^ ((hc >> 2) & 3);
        a[mt] = *(const short8*)&xs[p * 32 + slot * 8];
      }
#pragma unroll
      for (int mt = 0; mt < 4; mt++)
#pragma unroll
        for (int nt = 0; nt < 4; nt++)
          acc[mt][nt] = __builtin_amdgcn_mfma_f32_16x16x32_bf16(
              a[mt], bf[cur][nt], acc[mt][nt], 0, 0, 0);
    }
  }

  // ---- epilogue: 2 chunks of 32 co; float4 LDS bounce, + bias only ----
#pragma unroll
  for (int ch = 0; ch < 2; ch++) {
    __syncthreads();
#pragma unroll
    for (int mt = 0; mt < 4; mt++) {
      const int mtg = wave * 4 + mt;
      const int pr = mtg >> 1;
      const int cb = (mtg & 1) * 16;
#pragma unroll
      for (int ntl = 0; ntl < 2; ntl++) {
        const int k = ntl * 16 + n16;
        *(float4v*)&lout[k * 292 + pr * 36 + cb + quad * 4] = acc[mt][ch * 2 + ntl];
      }
    }
    __syncthreads();
#pragma unroll
    for (int it = 0; it < 8; it++) {
      const int idx4 = it * 256 + t;
      const int k = idx4 >> 6;
      const int rem = idx4 & 63;
      const int pr = rem >> 3;
      const int pw4 = (rem & 7) * 4;
      const int co = ch * 32 + k;
      const float4v v = *(const float4v*)&lout[k * 292 + pr * 36 + pw4];
      const float bias = bcomb[b * C_ + co];
      const size_t gi =
          (((size_t)b * C_ + co) * HW_ + (ty + pr)) * HW_ + (tx + pw4);
      float4v o;
      o.x = v.x + bias;
      o.y = v.y + bias;
      o.z = v.z + bias;
      o.w = v.w + bias;
      *(float4v*)(out + gi) = o;
    }
  }
}

// ---------------------------------------------------------------------------
extern "C" void kernel_launch(void* const* d_in, const int* in_sizes, int n_in,
                              void* d_out, int out_size, void* d_ws,
                              size_t ws_size, hipStream_t stream) {
  const float* x     = (const float*)d_in[0];
  const float* wg1   = (const float*)d_in[1];
  const float* bg1   = (const float*)d_in[2];
  const float* wg2   = (const float*)d_in[3];
  const float* bg2   = (const float*)d_in[4];
  const float* w_exp = (const float*)d_in[5];
  const float* b_exp = (const float*)d_in[6];
  float* out = (float*)d_out;

  // ws: ~1.2 MB total (poison cost matters: ~1.4 us/MB per iteration)
  float* ws = (float*)d_ws;
  float* pooled = ws;                               // 1024 floats
  float* bcomb  = ws + 1024;                        // 1024 floats
  __hip_bfloat16* wB = (__hip_bfloat16*)(ws + 2048);  // 589824 bf16

  pool_kernel<<<B_ * C_, 256, 0, stream>>>(x, pooled);
  combine_kernel<<<B_ * 8, 256, 0, stream>>>(w_exp, pooled, wg1, bg1, wg2, bg2,
                                             b_exp, wB, bcomb);
  conv_kernel<<<dim3(64, B_), 256, 0, stream>>>(x, wB, bcomb, out);
}

// Round 5
// 192.833 us; speedup vs baseline: 1.2427x; 1.2427x over previous
//
#include <hip/hip_runtime.h>
#include <hip/hip_bf16.h>
#include <math.h>

#define B_  16
#define C_  64
#define HW_ 128
#define E_  8
#define GH_ 16

typedef __attribute__((ext_vector_type(8))) short short8;
typedef __attribute__((ext_vector_type(4))) float float4v;

// conv tiling: full-width strips 128 wide x 4 rows; 512 threads (8 waves).
// M = 512 pixels = 32 M-tiles (row = mtg>>3, colt = mtg&7); each wave 4 Mt x 4 Nt.
#define STRIPS 32
#define ROWS_LDS 6
#define COLS_LDS 132                       // col_lds 0..129 valid (img col -1..128)
#define XS_SHORTS (ROWS_LDS * COLS_LDS * 32)  // 25344 shorts = 50688 B
// per-sample packed weights: [9 pos][2 khalf][4 quad][64 co][8 ci] bf16
#define WB_PER_B (9 * 2 * 4 * 64 * 8)      // 36864

// ---------------------------------------------------------------------------
// K1: global average pool. One block per (b,c); float4 loads, wave reduce.
// ---------------------------------------------------------------------------
__global__ __launch_bounds__(256) void pool_kernel(const float* __restrict__ x,
                                                   float* __restrict__ pooled) {
  const int bc = blockIdx.x;
  const float4v* p4 = (const float4v*)(x + (size_t)bc * (HW_ * HW_));
  float4v s4 = {0.f, 0.f, 0.f, 0.f};
  for (int i = threadIdx.x; i < (HW_ * HW_) / 4; i += 256) s4 += p4[i];
  float s = (s4.x + s4.y) + (s4.z + s4.w);
#pragma unroll
  for (int off = 32; off > 0; off >>= 1) s += __shfl_down(s, off, 64);
  __shared__ float red[4];
  if ((threadIdx.x & 63) == 0) red[threadIdx.x >> 6] = s;
  __syncthreads();
  if (threadIdx.x == 0)
    pooled[bc] = (red[0] + red[1] + red[2] + red[3]) * (1.0f / (HW_ * HW_));
}

// ---------------------------------------------------------------------------
// K2: fused gate + weight combine into packed bf16 B-fragment layout, with
// the residual identity folded into the center tap. block=(b, co-group of 8).
// ---------------------------------------------------------------------------
__global__ __launch_bounds__(256) void combine_kernel(
    const float* __restrict__ w_exp, const float* __restrict__ pooled,
    const float* __restrict__ wg1, const float* __restrict__ bg1,
    const float* __restrict__ wg2, const float* __restrict__ bg2,
    const float* __restrict__ b_exp, __hip_bfloat16* __restrict__ wB,
    float* __restrict__ bcomb) {
  __shared__ float wtmp[8 * 576];
  __shared__ float hsh[GH_];
  __shared__ float psh[E_];
  const int t = threadIdx.x;
  const int b = blockIdx.x >> 3;
  const int cog = blockIdx.x & 7;

  if (t < GH_) {
    float s = bg1[t];
    for (int c = 0; c < C_; c++)
      s = fmaf(pooled[b * C_ + c], wg1[c * GH_ + t], s);
    hsh[t] = fmaxf(s, 0.f);
  }
  __syncthreads();
  if (t == 0) {
    float p[E_];
    float mx = -1e30f;
#pragma unroll
    for (int e = 0; e < E_; e++) {
      float s = bg2[e];
#pragma unroll
      for (int g = 0; g < GH_; g++) s = fmaf(hsh[g], wg2[g * E_ + e], s);
      p[e] = s;
      mx = fmaxf(mx, s);
    }
    float sum = 0.f;
#pragma unroll
    for (int e = 0; e < E_; e++) { p[e] = expf(p[e] - mx); sum += p[e]; }
    const float inv = 1.0f / sum;
#pragma unroll
    for (int e = 0; e < E_; e++) p[e] *= inv;
    int i1 = 0;
#pragma unroll
    for (int e = 1; e < E_; e++) if (p[e] > p[i1]) i1 = e;
    int i2 = -1;
#pragma unroll
    for (int e = 0; e < E_; e++) {
      if (e == i1) continue;
      if (i2 < 0 || p[e] > p[i2]) i2 = e;
    }
    const float denom = p[i1] + p[i2] + 1e-8f;
#pragma unroll
    for (int e = 0; e < E_; e++)
      psh[e] = (e == i1 || e == i2) ? (p[e] / denom) : 0.f;
  }
  __syncthreads();
  float pb[E_];
#pragma unroll
  for (int e = 0; e < E_; e++) pb[e] = psh[e];

  const size_t src0 = (size_t)cog * 8 * 576;
  for (int i = t; i < 4608; i += 256) {
    float s = 0.f;
#pragma unroll
    for (int e = 0; e < E_; e++)
      s = fmaf(pb[e], w_exp[(size_t)e * (C_ * 576) + src0 + i], s);
    wtmp[i] = s;
  }
  __syncthreads();
  for (int i = t; i < 4608; i += 256) {
    const int j = i & 7;
    const int co_l = (i >> 3) & 7;
    const int rest = i >> 6;
    const int quad = rest & 3;
    const int khalf = (rest >> 2) & 1;
    const int pos = rest >> 3;
    const int ci = khalf * 32 + quad * 8 + j;
    const int co = cog * 8 + co_l;
    float v = wtmp[co_l * 576 + ci * 9 + pos];
    if (pos == 4 && co == ci) v += 1.0f;   // fold residual into conv
    wB[(size_t)b * WB_PER_B +
       ((((pos * 2 + khalf) * 4 + quad) * 64) + co) * 8 + j] =
        __float2bfloat16(v);
  }
  if (t < 8) {
    const int co = cog * 8 + t;
    float s = 0.f;
#pragma unroll
    for (int e = 0; e < E_; e++) s = fmaf(pb[e], b_exp[e * C_ + co], s);
    bcomb[b * C_ + co] = s;
  }
}

// ---------------------------------------------------------------------------
// K3: implicit-GEMM conv, full-width strips. fp32 NCHW x staged as aligned
// 512-B row segments -> bf16 LDS (in-flight convert). Residual folded in wB.
// Direct float4 stores from C-layout. grid = 512 blocks x 512 threads.
// ---------------------------------------------------------------------------
__global__ __launch_bounds__(512, 4) void conv_kernel(
    const float* __restrict__ x, const __hip_bfloat16* __restrict__ wB,
    const float* __restrict__ bcomb, float* __restrict__ out) {
  __shared__ __align__(16) short xs[XS_SHORTS];

  const int t = threadIdx.x;
  const int blk = blockIdx.x;
  // XCD-aware decode (assumes round-robin blk%8 -> XCD; perf heuristic only):
  // XCD k owns samples 2k,2k+1, all strips.
  const int xcd = blk & 7;
  const int idx = blk >> 3;               // 0..63
  const int b = xcd * 2 + (idx >> 5);
  const int strip = idx & 31;
  const int ty = strip * 4;

  const int wave = t >> 6;
  const int L = t & 63;
  const int n16 = L & 15;
  const int quad = L >> 4;

  // staging decode: 512 threads = 16 ci-pairs x 32 col-quads
  const int s_cq = t & 31;
  const int s_p = t >> 5;                 // 0..15

  float bias[4];
#pragma unroll
  for (int nt = 0; nt < 4; nt++) bias[nt] = bcomb[b * C_ + nt * 16 + n16];

  float4v acc[4][4];
#pragma unroll
  for (int mt = 0; mt < 4; mt++)
#pragma unroll
    for (int nt = 0; nt < 4; nt++) acc[mt][nt] = (float4v)0.f;

  for (int h = 0; h < 2; h++) {
    __syncthreads();
    // ---- stage 6 rows x 128 cols x 32 ci (fp32 -> bf16, paired-ci b32) ----
#pragma unroll
    for (int r = 0; r < ROWS_LDS; r++) {
      const int gh = ty + r - 1;
      const int ci = h * 32 + s_p * 2;
      float4v vA = {0.f, 0.f, 0.f, 0.f};
      float4v vB = {0.f, 0.f, 0.f, 0.f};
      if ((unsigned)gh < (unsigned)HW_) {
        const float* pA =
            x + (((size_t)(b * C_ + ci) * HW_ + gh) * HW_ + s_cq * 4);
        vA = *(const float4v*)pA;
        vB = *(const float4v*)(pA + HW_ * HW_);
      }
#pragma unroll
      for (int kk = 0; kk < 4; kk++) {
        const int cl = s_cq * 4 + kk + 1;         // col_lds 1..128
        const int slot = (s_p >> 2) ^ ((cl >> 1) & 3);
        __hip_bfloat16 ba = __float2bfloat16(vA[kk]);
        __hip_bfloat16 bb = __float2bfloat16(vB[kk]);
        const unsigned pk = (unsigned)*(unsigned short*)&ba |
                            ((unsigned)*(unsigned short*)&bb << 16);
        *(unsigned*)&xs[((r * COLS_LDS + cl) * 4 + slot) * 8 + (s_p & 3) * 2] =
            pk;
      }
      // zero-pad edge columns (img col -1 and 128)
      if (t < 32) {
        const int p2 = t & 15;
        const int cl = (t >> 4) ? 129 : 0;
        const int slot = (p2 >> 2) ^ ((cl >> 1) & 3);
        *(unsigned*)&xs[((r * COLS_LDS + cl) * 4 + slot) * 8 + (p2 & 3) * 2] =
            0u;
      }
    }
    __syncthreads();

    // ---- B fragments: double-buffered prefetch from global (L2-hot) ----
    const __hip_bfloat16* wBh =
        wB + (size_t)b * WB_PER_B + (size_t)(h * 4 + quad) * 512 + n16 * 8;
    short8 bf[2][4];
#pragma unroll
    for (int nt = 0; nt < 4; nt++)
      bf[0][nt] = *(const short8*)(wBh + nt * 128);

#pragma unroll
    for (int pos = 0; pos < 9; pos++) {
      const int cur = pos & 1;
      if (pos < 8) {
#pragma unroll
        for (int nt = 0; nt < 4; nt++)
          bf[cur ^ 1][nt] =
              *(const short8*)(wBh + (size_t)(pos + 1) * 4096 + nt * 128);
      }
      const int kh = pos / 3;
      const int kw = pos - kh * 3;
      short8 a[4];
#pragma unroll
      for (int mt = 0; mt < 4; mt++) {
        const int mtg = wave * 4 + mt;
        const int lr = (mtg >> 3) + kh;           // 0..5
        const int cl = (mtg & 7) * 16 + n16 + kw; // 0..129
        const int slot = quad ^ ((cl >> 1) & 3);
        a[mt] = *(const short8*)&xs[((lr * COLS_LDS + cl) * 4 + slot) * 8];
      }
#pragma unroll
      for (int mt = 0; mt < 4; mt++)
#pragma unroll
        for (int nt = 0; nt < 4; nt++)
          acc[mt][nt] = __builtin_amdgcn_mfma_f32_16x16x32_bf16(
              a[mt], bf[cur][nt], acc[mt][nt], 0, 0, 0);
    }
  }

  // ---- epilogue: direct float4 stores (4 regs = 4 consecutive img cols) ----
#pragma unroll
  for (int mt = 0; mt < 4; mt++) {
    const int mtg = wave * 4 + mt;
    const int row = ty + (mtg >> 3);
    const int cb = (mtg & 7) * 16 + quad * 4;
#pragma unroll
    for (int nt = 0; nt < 4; nt++) {
      float4v o = acc[mt][nt];
      o.x += bias[nt];
      o.y += bias[nt];
      o.z += bias[nt];
      o.w += bias[nt];
      *(float4v*)(out +
                  ((size_t)(b * C_ + nt * 16 + n16) * HW_ + row) * HW_ + cb) = o;
    }
  }
}

// ---------------------------------------------------------------------------
extern "C" void kernel_launch(void* const* d_in, const int* in_sizes, int n_in,
                              void* d_out, int out_size, void* d_ws,
                              size_t ws_size, hipStream_t stream) {
  const float* x     = (const float*)d_in[0];
  const float* wg1   = (const float*)d_in[1];
  const float* bg1   = (const float*)d_in[2];
  const float* wg2   = (const float*)d_in[3];
  const float* bg2   = (const float*)d_in[4];
  const float* w_exp = (const float*)d_in[5];
  const float* b_exp = (const float*)d_in[6];
  float* out = (float*)d_out;

  float* ws = (float*)d_ws;
  float* pooled = ws;                                 // 1024 floats
  float* bcomb  = ws + 1024;                          // 1024 floats
  __hip_bfloat16* wB = (__hip_bfloat16*)(ws + 2048);  // 589824 bf16 (~1.2 MB ws)

  pool_kernel<<<B_ * C_, 256, 0, stream>>>(x, pooled);
  combine_kernel<<<B_ * 8, 256, 0, stream>>>(w_exp, pooled, wg1, bg1, wg2, bg2,
                                             b_exp, wB, bcomb);
  conv_kernel<<<512, 512, 0, stream>>>(x, wB, bcomb, out);
}

// Round 6
// 188.221 us; speedup vs baseline: 1.2731x; 1.0245x over previous
//
#include <hip/hip_runtime.h>
#include <hip/hip_bf16.h>
#include <math.h>

#define B_  16
#define C_  64
#define HW_ 128
#define E_  8
#define GH_ 16

typedef __attribute__((ext_vector_type(8))) short short8;
typedef __attribute__((ext_vector_type(4))) float float4v;

// conv tiling: full-width strips 128 wide x 2 rows; 256 threads (4 waves).
// M = 256 pixels = 16 M-tiles (row = mtg>>3, coltile = mtg&7); wave = 4Mt x 4Nt.
#define ROWS_LDS 4
#define COLS_LDS 132                      // col_lds 0..129 valid (img col -1..128)
#define XS_SHORTS (ROWS_LDS * COLS_LDS * 32)  // 16896 shorts = 33792 B
// per-sample packed weights: [9 pos][2 khalf][4 quad][64 co][8 ci] bf16
#define WB_PER_B (9 * 2 * 4 * 64 * 8)     // 36864

// ---------------------------------------------------------------------------
// K1: global average pool. One block per (b,c); float4 loads, wave reduce.
// ---------------------------------------------------------------------------
__global__ __launch_bounds__(256) void pool_kernel(const float* __restrict__ x,
                                                   float* __restrict__ pooled) {
  const int bc = blockIdx.x;
  const float4v* p4 = (const float4v*)(x + (size_t)bc * (HW_ * HW_));
  float4v s4 = {0.f, 0.f, 0.f, 0.f};
  for (int i = threadIdx.x; i < (HW_ * HW_) / 4; i += 256) s4 += p4[i];
  float s = (s4.x + s4.y) + (s4.z + s4.w);
#pragma unroll
  for (int off = 32; off > 0; off >>= 1) s += __shfl_down(s, off, 64);
  __shared__ float red[4];
  if ((threadIdx.x & 63) == 0) red[threadIdx.x >> 6] = s;
  __syncthreads();
  if (threadIdx.x == 0)
    pooled[bc] = (red[0] + red[1] + red[2] + red[3]) * (1.0f / (HW_ * HW_));
}

// ---------------------------------------------------------------------------
// K2: fused gate + weight combine into packed bf16 B-fragment layout, with
// the residual identity folded into the center tap. block=(b, co-group of 8).
// ---------------------------------------------------------------------------
__global__ __launch_bounds__(256) void combine_kernel(
    const float* __restrict__ w_exp, const float* __restrict__ pooled,
    const float* __restrict__ wg1, const float* __restrict__ bg1,
    const float* __restrict__ wg2, const float* __restrict__ bg2,
    const float* __restrict__ b_exp, __hip_bfloat16* __restrict__ wB,
    float* __restrict__ bcomb) {
  __shared__ float wtmp[8 * 576];
  __shared__ float hsh[GH_];
  __shared__ float psh[E_];
  const int t = threadIdx.x;
  const int b = blockIdx.x >> 3;
  const int cog = blockIdx.x & 7;

  if (t < GH_) {
    float s = bg1[t];
    for (int c = 0; c < C_; c++)
      s = fmaf(pooled[b * C_ + c], wg1[c * GH_ + t], s);
    hsh[t] = fmaxf(s, 0.f);
  }
  __syncthreads();
  if (t == 0) {
    float p[E_];
    float mx = -1e30f;
#pragma unroll
    for (int e = 0; e < E_; e++) {
      float s = bg2[e];
#pragma unroll
      for (int g = 0; g < GH_; g++) s = fmaf(hsh[g], wg2[g * E_ + e], s);
      p[e] = s;
      mx = fmaxf(mx, s);
    }
    float sum = 0.f;
#pragma unroll
    for (int e = 0; e < E_; e++) { p[e] = expf(p[e] - mx); sum += p[e]; }
    const float inv = 1.0f / sum;
#pragma unroll
    for (int e = 0; e < E_; e++) p[e] *= inv;
    int i1 = 0;
#pragma unroll
    for (int e = 1; e < E_; e++) if (p[e] > p[i1]) i1 = e;
    int i2 = -1;
#pragma unroll
    for (int e = 0; e < E_; e++) {
      if (e == i1) continue;
      if (i2 < 0 || p[e] > p[i2]) i2 = e;
    }
    const float denom = p[i1] + p[i2] + 1e-8f;
#pragma unroll
    for (int e = 0; e < E_; e++)
      psh[e] = (e == i1 || e == i2) ? (p[e] / denom) : 0.f;
  }
  __syncthreads();
  float pb[E_];
#pragma unroll
  for (int e = 0; e < E_; e++) pb[e] = psh[e];

  const size_t src0 = (size_t)cog * 8 * 576;
  for (int i = t; i < 4608; i += 256) {
    float s = 0.f;
#pragma unroll
    for (int e = 0; e < E_; e++)
      s = fmaf(pb[e], w_exp[(size_t)e * (C_ * 576) + src0 + i], s);
    wtmp[i] = s;
  }
  __syncthreads();
  for (int i = t; i < 4608; i += 256) {
    const int j = i & 7;
    const int co_l = (i >> 3) & 7;
    const int rest = i >> 6;
    const int quad = rest & 3;
    const int khalf = (rest >> 2) & 1;
    const int pos = rest >> 3;
    const int ci = khalf * 32 + quad * 8 + j;
    const int co = cog * 8 + co_l;
    float v = wtmp[co_l * 576 + ci * 9 + pos];
    if (pos == 4 && co == ci) v += 1.0f;   // fold residual into conv
    wB[(size_t)b * WB_PER_B +
       ((((pos * 2 + khalf) * 4 + quad) * 64) + co) * 8 + j] =
        __float2bfloat16(v);
  }
  if (t < 8) {
    const int co = cog * 8 + t;
    float s = 0.f;
#pragma unroll
    for (int e = 0; e < E_; e++) s = fmaf(pb[e], b_exp[e * C_ + co], s);
    bcomb[b * C_ + co] = s;
  }
}

// ---------------------------------------------------------------------------
// K3: implicit-GEMM conv, 2-row full-width strips, 256 threads (4 waves).
// Each staging thread loads float4 from 8 consecutive ci planes and writes
// full 16-B (8-ci) LDS chunks: slot = grp ^ (s_cq & 3)  (s_cq = (cl-1)>>2).
// A-frag reads stay 2-way (free); writes are 4-way on 8 instrs (cheap).
// Residual folded in wB; direct stores, 128-B line halves paired. grid 1024.
// ---------------------------------------------------------------------------
__global__ __launch_bounds__(256, 4) void conv_kernel(
    const float* __restrict__ x, const __hip_bfloat16* __restrict__ wB,
    const float* __restrict__ bcomb, float* __restrict__ out) {
  __shared__ __align__(16) short xs[XS_SHORTS];

  const int t = threadIdx.x;
  const int blk = blockIdx.x;
  // XCD-aware decode: XCD k owns samples 2k,2k+1; strips ordered within.
  const int xcd = blk & 7;
  const int idx = blk >> 3;               // 0..127
  const int b = xcd * 2 + (idx >> 6);
  const int strip = idx & 63;
  const int ty = strip * 2;

  const int wave = t >> 6;
  const int L = t & 63;
  const int n16 = L & 15;
  const int quad = L >> 4;

  float bias[4];
#pragma unroll
  for (int nt = 0; nt < 4; nt++) bias[nt] = bcomb[b * C_ + nt * 16 + n16];

  float4v acc[4][4];
#pragma unroll
  for (int mt = 0; mt < 4; mt++)
#pragma unroll
    for (int nt = 0; nt < 4; nt++) acc[mt][nt] = (float4v)0.f;

  for (int h = 0; h < 2; h++) {
    __syncthreads();
    // ---- stage 4 rows x 128 cols x 32 ci: 512 chunk-builds, 2 per thread ----
#pragma unroll
    for (int it = 0; it < 2; it++) {
      const int i = it * 256 + t;
      const int scq = i & 31;             // col-quad
      const int grp = (i >> 5) & 3;       // 8-ci group within half
      const int r = i >> 7;               // 0..3
      const int gh = ty + r - 1;
      const int ci = h * 32 + grp * 8;
      float4v v[8];
      if ((unsigned)gh < (unsigned)HW_) {
        const float* p =
            x + ((size_t)(b * C_ + ci) * HW_ + gh) * HW_ + scq * 4;
#pragma unroll
        for (int k = 0; k < 8; k++)
          v[k] = *(const float4v*)(p + (size_t)k * (HW_ * HW_));
      } else {
#pragma unroll
        for (int k = 0; k < 8; k++) v[k] = (float4v)0.f;
      }
      const int slot = grp ^ (scq & 3);
#pragma unroll
      for (int kk = 0; kk < 4; kk++) {
        const int cl = scq * 4 + kk + 1;  // 1..128
        short8 pk;
#pragma unroll
        for (int k = 0; k < 8; k++) {
          __hip_bfloat16 bb = __float2bfloat16(v[k][kk]);
          pk[k] = *(short*)&bb;
        }
        *(short8*)&xs[((r * COLS_LDS + cl) * 4 + slot) * 8] = pk;
      }
    }
    // zero-pad edge columns (img col -1 and 128), all 4 slots
    if (t < 32) {
      const int r = t >> 3;
      const int edge = (t >> 2) & 1;
      const int slot = t & 3;
      const int cl = edge ? 129 : 0;
      *(short8*)&xs[((r * COLS_LDS + cl) * 4 + slot) * 8] = (short8)0;
    }
    __syncthreads();

    // ---- B fragments: double-buffered prefetch from global (L2-hot) ----
    const __hip_bfloat16* wBh =
        wB + (size_t)b * WB_PER_B + (size_t)(h * 4 + quad) * 512 + n16 * 8;
    short8 bf[2][4];
#pragma unroll
    for (int nt = 0; nt < 4; nt++)
      bf[0][nt] = *(const short8*)(wBh + nt * 128);

#pragma unroll
    for (int pos = 0; pos < 9; pos++) {
      const int cur = pos & 1;
      if (pos < 8) {
#pragma unroll
        for (int nt = 0; nt < 4; nt++)
          bf[cur ^ 1][nt] =
              *(const short8*)(wBh + (size_t)(pos + 1) * 4096 + nt * 128);
      }
      const int kh = pos / 3;
      const int kw = pos - kh * 3;
      short8 a[4];
#pragma unroll
      for (int mt = 0; mt < 4; mt++) {
        const int mtg = wave * 4 + mt;
        const int lr = (mtg >> 3) + kh;            // 0..3
        const int cl = (mtg & 7) * 16 + n16 + kw;  // 0..129
        const int slot = quad ^ (((cl - 1) >> 2) & 3);
        a[mt] = *(const short8*)&xs[((lr * COLS_LDS + cl) * 4 + slot) * 8];
      }
#pragma unroll
      for (int mt = 0; mt < 4; mt++)
#pragma unroll
        for (int nt = 0; nt < 4; nt++)
          acc[mt][nt] = __builtin_amdgcn_mfma_f32_16x16x32_bf16(
              a[mt], bf[cur][nt], acc[mt][nt], 0, 0, 0);
    }
  }

  // ---- epilogue: direct float4 stores; pair the two 64-B halves of each
  // 128-B line (adjacent coltiles = adjacent mt) back-to-back ----
#pragma unroll
  for (int mtp = 0; mtp < 4; mtp += 2) {
#pragma unroll
    for (int nt = 0; nt < 4; nt++) {
#pragma unroll
      for (int d = 0; d < 2; d++) {
        const int mt = mtp + d;
        const int mtg = wave * 4 + mt;
        const int row = ty + (mtg >> 3);
        const int cb = (mtg & 7) * 16 + quad * 4;
        float4v o = acc[mt][nt];
        o.x += bias[nt];
        o.y += bias[nt];
        o.z += bias[nt];
        o.w += bias[nt];
        *(float4v*)(out +
                    ((size_t)(b * C_ + nt * 16 + n16) * HW_ + row) * HW_ + cb) =
            o;
      }
    }
  }
}

// ---------------------------------------------------------------------------
extern "C" void kernel_launch(void* const* d_in, const int* in_sizes, int n_in,
                              void* d_out, int out_size, void* d_ws,
                              size_t ws_size, hipStream_t stream) {
  const float* x     = (const float*)d_in[0];
  const float* wg1   = (const float*)d_in[1];
  const float* bg1   = (const float*)d_in[2];
  const float* wg2   = (const float*)d_in[3];
  const float* bg2   = (const float*)d_in[4];
  const float* w_exp = (const float*)d_in[5];
  const float* b_exp = (const float*)d_in[6];
  float* out = (float*)d_out;

  float* ws = (float*)d_ws;
  float* pooled = ws;                                 // 1024 floats
  float* bcomb  = ws + 1024;                          // 1024 floats
  __hip_bfloat16* wB = (__hip_bfloat16*)(ws + 2048);  // 589824 bf16 (~1.2 MB ws)

  pool_kernel<<<B_ * C_, 256, 0, stream>>>(x, pooled);
  combine_kernel<<<B_ * 8, 256, 0, stream>>>(w_exp, pooled, wg1, bg1, wg2, bg2,
                                             b_exp, wB, bcomb);
  conv_kernel<<<1024, 256, 0, stream>>>(x, wB, bcomb, out);
}